// Round 10
// baseline (105.772 us; speedup 1.0000x reference)
//
#include <hip/hip_runtime.h>
#include <hip/hip_bf16.h>

#define B_ 8
#define T_ 12
#define N_ 2048
#define C_ 64
#define BM 128
#define BK 32

typedef __attribute__((ext_vector_type(4))) float f32x4;
typedef __attribute__((ext_vector_type(4))) __bf16 bf16x4;
typedef __attribute__((ext_vector_type(8))) __bf16 bf16x8;

#define GAS __attribute__((address_space(1)))
#define LAS __attribute__((address_space(3)))

static __device__ __forceinline__ void gld_lds16(const void* g, void* l) {
    __builtin_amdgcn_global_load_lds((const GAS void*)g, (LAS void*)l, 16, 0, 0);
}

// ws layout (bytes)
#define WS_CBUF 0
#define WS_WTB  1024                                   // 16 KB
#define WS_ADJB 32768                                  // 8 MB (row-major bf16 adj)
#define WS_P1T  (32768 + 8388608)                      // 24 MB
#define WS_P0S  (WS_P1T + 25165824)                    // 24 MB (full tier only)
#define WS_MID  ((size_t)WS_P0S)                       // 33,587,200 (proven available)
#define WS_FULL ((size_t)WS_P0S + 25165824)            // 58,753,024

// ---------------- lambda MLP (fallback path) ----------------
__global__ void lam_kernel(const float* __restrict__ st, const float* __restrict__ W1,
                           const float* __restrict__ b1, const float* __restrict__ W2,
                           const float* __restrict__ b2, float* __restrict__ cbuf) {
    const int t = threadIdx.x >> 5;
    const int h = threadIdx.x & 31;
    if (t >= T_) return;
    float acc = b1[h];
    #pragma unroll 8
    for (int e = 0; e < 64; ++e) acc += st[t * 64 + e] * W1[e * 32 + h];
    float hv = fmaxf(acc, 0.f) * W2[h];
    #pragma unroll
    for (int off = 16; off; off >>= 1) hv += __shfl_down(hv, off, 32);
    if (h == 0) {
        float lam = 1.f + fmaxf(hv + b2[0], 0.f);
        cbuf[t]      = 2.f - 2.f / lam;
        cbuf[T_ + t] = 2.f / lam;
    }
}

// ---------------- lambda MLP + Wcat->bf16 ----------------
__global__ void lamw_kernel(const float* __restrict__ st, const float* __restrict__ W1,
                            const float* __restrict__ b1, const float* __restrict__ W2,
                            const float* __restrict__ b2, const float* __restrict__ weights,
                            float* __restrict__ cbuf, __bf16* __restrict__ WtB) {
    const int t = threadIdx.x >> 5;
    const int h = threadIdx.x & 31;
    if (t < T_) {
        float acc = b1[h];
        #pragma unroll 8
        for (int e = 0; e < 64; ++e) acc += st[t * 64 + e] * W1[e * 32 + h];
        float hv = fmaxf(acc, 0.f) * W2[h];
        #pragma unroll
        for (int off = 16; off; off >>= 1) hv += __shfl_down(hv, off, 32);
        if (h == 0) {
            float lam = 1.f + fmaxf(hv + b2[0], 0.f);
            cbuf[t]      = 2.f - 2.f / lam;
            cbuf[T_ + t] = 2.f / lam;
        }
    }
    // WtB[o][k]: k<64 -> weights[1][k][o] (adj support), k>=64 -> weights[0][k-64][o] (identity)
    for (int e = threadIdx.x; e < 64 * 128; e += 512) {
        int o = e >> 7, k = e & 127;
        float v = (k < 64) ? weights[4096 + k * 64 + o] : weights[(k - 64) * 64 + o];
        WtB[o * 128 + k] = (__bf16)v;
    }
}

// ---------------- P kernel (round-5 verified): P1T = (x@W1)^T bf16 ; P0 = c1*(x@W0)+bias ; + adj cvt ----------------
template<bool FULLP>
__global__ __launch_bounds__(256, 4) void pcvt_kernel(
    const float* __restrict__ x, const float* __restrict__ adj,
    const __bf16* __restrict__ WtB, const float* __restrict__ cbuf,
    const float* __restrict__ bias, __bf16* __restrict__ adjb,
    __bf16* __restrict__ P1T, __bf16* __restrict__ P0S, float* __restrict__ out)
{
    const int bid = blockIdx.x;
    const int tid = threadIdx.x;
    if (bid >= 1536) {
        const size_t i = ((size_t)(bid - 1536) * 256 + tid) * 8;
        const float4 f0 = *(const float4*)&adj[i];
        const float4 f1 = *(const float4*)&adj[i + 4];
        bf16x8 h = { (__bf16)f0.x, (__bf16)f0.y, (__bf16)f0.z, (__bf16)f0.w,
                     (__bf16)f1.x, (__bf16)f1.y, (__bf16)f1.z, (__bf16)f1.w };
        *(bf16x8*)&adjb[i] = h;
        return;
    }
    __shared__ __align__(16) __bf16 T[64 * 128];
    char* TB = (char*)T;
    const int bt = bid >> 4, n0 = (bid & 15) * 128;
    const int l = tid & 63, w = tid >> 6;
    const int lr = l & 15, lk = l >> 4;
    const float c1 = cbuf[bt % T_];

    f32x4 p1[2][4] = {}, p0[2][4] = {};
    #pragma unroll
    for (int ks = 0; ks < 2; ++ks) {
        bf16x8 a[2];
        #pragma unroll
        for (int mi = 0; mi < 2; ++mi) {
            const float* xs = x + ((size_t)bt * N_ + n0 + w * 32 + mi * 16 + lr) * C_ + ks * 32 + lk * 8;
            float4 f0 = *(const float4*)xs;
            float4 f1 = *(const float4*)(xs + 4);
            a[mi] = { (__bf16)f0.x, (__bf16)f0.y, (__bf16)f0.z, (__bf16)f0.w,
                      (__bf16)f1.x, (__bf16)f1.y, (__bf16)f1.z, (__bf16)f1.w };
        }
        #pragma unroll
        for (int nj = 0; nj < 4; ++nj) {
            const __bf16* wb = WtB + (nj * 16 + lr) * 128 + ks * 32 + lk * 8;
            bf16x8 b1v = *(const bf16x8*)wb;
            bf16x8 b0v = *(const bf16x8*)(wb + 64);
            #pragma unroll
            for (int mi = 0; mi < 2; ++mi) {
                p1[mi][nj] = __builtin_amdgcn_mfma_f32_16x16x32_bf16(a[mi], b1v, p1[mi][nj], 0, 0, 0);
                p0[mi][nj] = __builtin_amdgcn_mfma_f32_16x16x32_bf16(a[mi], b0v, p0[mi][nj], 0, 0, 0);
            }
        }
    }
    #pragma unroll
    for (int nj = 0; nj < 4; ++nj) {
        const int o = nj * 16 + lr;
        const float bv = bias[o];
        #pragma unroll
        for (int mi = 0; mi < 2; ++mi)
            #pragma unroll
            for (int q = 0; q < 4; ++q) {
                const int row = w * 32 + mi * 16 + lk * 4 + q;
                const size_t idx = ((size_t)bt * N_ + n0 + row) * C_ + o;
                const float v = c1 * p0[mi][nj][q] + bv;
                if (FULLP) P0S[idx] = (__bf16)v; else out[idx] = v;
            }
    }
    #pragma unroll
    for (int nj = 0; nj < 4; ++nj) {
        const int o = nj * 16 + lr;
        #pragma unroll
        for (int mi = 0; mi < 2; ++mi)
            #pragma unroll
            for (int q = 0; q < 4; ++q) {
                const int row = w * 32 + mi * 16 + lk * 4 + q;
                *(__bf16*)(TB + o * 256 + ((row * 2) ^ ((o & 7) << 4))) = (__bf16)p1[mi][nj][q];
            }
    }
    __syncthreads();
    {
        const int o = tid >> 2, seg = tid & 3;
        __bf16* dst = P1T + ((size_t)bt * 64 + o) * N_ + n0 + seg * 32;
        #pragma unroll
        for (int i = 0; i < 4; ++i) {
            const int chunk = seg * 64 + i * 16;
            *(bf16x8*)(dst + i * 8) = *(const bf16x8*)(TB + o * 256 + (chunk ^ ((o & 7) << 4)));
        }
    }
}

// ---------------- main kernel: out = c2*(adj @ P1) + P0term ----------------
// BK=32, TRIPLE-buffered 3x16KB LDS, prefetch depth 2, counted vmcnt(4).
// Grid 768 (1D, XCD-swizzled: each XCD owns 6 btg x 16 m), 3 blocks/CU.
template<bool FULLP>
__global__ __launch_bounds__(256, 3) void dgcn_main8(
    const __bf16* __restrict__ adjb, const __bf16* __restrict__ P1T,
    const __bf16* __restrict__ P0S, const float* __restrict__ cbuf,
    float* __restrict__ out)
{
    __shared__ __align__(16) __bf16 smem[24576];   // 49152 B = 3 x 16 KB {A 8K | B 8K}
    char* sb = (char*)smem;

    // XCD swizzle: id%8 = XCD; each XCD gets 6 contiguous btg (B-panels ~3MB, L2-resident)
    const int id   = blockIdx.x;                   // 0..767
    const int xcd  = id & 7;
    const int wi   = id >> 3;                      // 0..95
    const int btg  = xcd * 6 + (wi >> 4);          // 0..47
    const int m0   = (wi & 15) * BM;

    const int tid = threadIdx.x;
    const int l   = tid & 63, w = tid >> 6;
    const int wr  = w >> 1, wc = w & 1;
    const int lr  = l & 15, lk = l >> 4;

    // staging sources: per wave, instruction i in {0,1}: slots s = (w*2+i)*64 + l
    // A: r = s>>2, j = s&3, src col chunk = j ^ ((r>>1)&3)   (row = 64 B = 4 slots)
    // B: bb = s>>8, o = (s>>2)&63, j = s&3, chunk = j ^ ((o>>1)&3)
    const __bf16* srcA[2];
    const __bf16* srcB[2];
    #pragma unroll
    for (int i = 0; i < 2; ++i) {
        int s = (w * 2 + i) * 64 + l;              // 0..511
        int r = s >> 2, j = s & 3;
        srcA[i] = adjb + (size_t)(m0 + r) * N_ + 8 * (j ^ ((r >> 1) & 3));
        int bb = s >> 8, o = (s >> 2) & 63;
        srcB[i] = P1T + ((size_t)(btg * 2 + bb) * 64 + o) * N_ + 8 * (j ^ ((o >> 1) & 3));
    }

    f32x4 acc[4][4] = {};

    auto STAGE = [&]__attribute__((always_inline))(char* buf) {   // 4 gld_lds / thread
        #pragma unroll
        for (int i = 0; i < 2; ++i) {
            gld_lds16(srcA[i], buf + (w * 2 + i) * 1024);
            gld_lds16(srcB[i], buf + 8192 + (w * 2 + i) * 1024);
            srcA[i] += BK;
            srcB[i] += BK;
        }
    };
    auto COMPUTE = [&]__attribute__((always_inline))(const char* base) {
        bf16x8 a[4];
        #pragma unroll
        for (int mi = 0; mi < 4; ++mi) {
            int rr = wr * 64 + mi * 16 + lr;
            a[mi] = *(const bf16x8*)(base + rr * 64 + 16 * (lk ^ ((rr >> 1) & 3)));
        }
        #pragma unroll
        for (int nj = 0; nj < 4; ++nj) {
            int cc = nj * 16 + lr;
            bf16x8 b = *(const bf16x8*)(base + 8192 + wc * 4096 + cc * 64 + 16 * (lk ^ ((cc >> 1) & 3)));
            #pragma unroll
            for (int mi = 0; mi < 4; ++mi)
                acc[mi][nj] = __builtin_amdgcn_mfma_f32_16x16x32_bf16(a[mi], b, acc[mi][nj], 0, 0, 0);
        }
    };

    const int NT = N_ / BK;                        // 64
    // prologue: groups for kt=0 (buf0) and kt=1 (buf1)
    STAGE(sb);
    STAGE(sb + 16384);

    #pragma unroll 1
    for (int kt = 0; kt < NT; ++kt) {
        // retire group(kt); group(kt+1)'s 4 ops may stay in flight
        if (kt == NT - 1) asm volatile("s_waitcnt vmcnt(0)" ::: "memory");
        else              asm volatile("s_waitcnt vmcnt(4)" ::: "memory");
        __builtin_amdgcn_sched_barrier(0);
        __builtin_amdgcn_s_barrier();              // buf(kt) ready for all waves
        char* base = sb + (kt % 3) * 16384;
        COMPUTE(base);
        __builtin_amdgcn_s_barrier();              // all waves done reading buf(kt)
        if (kt + 2 < NT) STAGE(sb + ((kt + 2) % 3) * 16384);
    }

    // lean epilogue: out = c2*acc + P0term   (wave wc owns bt = btg*2+wc)
    const int btA = btg * 2 + wc;
    const float c2 = cbuf[T_ + (btA % T_)];
    #pragma unroll
    for (int nj = 0; nj < 4; ++nj) {
        const int o = nj * 16 + lr;
        #pragma unroll
        for (int mi = 0; mi < 4; ++mi)
            #pragma unroll
            for (int q = 0; q < 4; ++q) {
                const int row = wr * 64 + mi * 16 + lk * 4 + q;
                const size_t idx = ((size_t)btA * N_ + m0 + row) * C_ + o;
                const float p0v = FULLP ? (float)P0S[idx] : out[idx];
                out[idx] = c2 * acc[mi][nj][q] + p0v;
            }
    }
}

// ---------------- fallback (round-1 verified) ----------------
#define LDM 72
#define LDE 136
__global__ __launch_bounds__(256, 3) void dgcn_fb(
    const float* __restrict__ x, const float* __restrict__ adj,
    const float* __restrict__ weights, const float* __restrict__ bias,
    const float* __restrict__ cbuf, float* __restrict__ out)
{
    __shared__ __align__(16) __bf16 smem[BM * LDE];
    __shared__ __align__(16) __bf16 Wt[64 * LDE];
    __bf16* As = smem;
    __bf16* Bs = smem + BM * LDM;
    __bf16* E  = smem;

    const int mtile = blockIdx.x;
    const int bt    = blockIdx.y;
    const int tloc  = bt % T_;
    const int m0    = mtile * BM;
    const int tid   = threadIdx.x;
    const int lane  = tid & 63;
    const int w     = tid >> 6;

    const float c1 = cbuf[tloc];
    const float c2 = cbuf[T_ + tloc];
    const float* xbt = x + (size_t)bt * N_ * C_;

    for (int e = tid; e < 2 * 64 * 64; e += 256) {
        int kk = e >> 6, o = e & 63;
        float v = (kk < 64) ? weights[4096 + kk * 64 + o] : weights[(kk - 64) * 64 + o];
        Wt[o * LDE + kk] = (__bf16)v;
    }

    f32x4 acc[2][4] = {};
    const int c4 = tid & 15;
    const int rg = tid >> 4;
    const int lr = lane & 15;
    const int lk = lane >> 4;

    for (int kt = 0; kt < N_ / 64; ++kt) {
        const int k0 = kt * 64;
        __syncthreads();
        #pragma unroll
        for (int j = 0; j < 8; ++j) {
            const int r = rg + 16 * j;
            const float4 f = *(const float4*)&adj[(size_t)(m0 + r) * N_ + k0 + 4 * c4];
            bf16x4 h = { (__bf16)f.x, (__bf16)f.y, (__bf16)f.z, (__bf16)f.w };
            *(bf16x4*)&As[r * LDM + 4 * c4] = h;
        }
        #pragma unroll
        for (int j = 0; j < 4; ++j) {
            const int k  = (tid & 15) + 16 * j;
            const int c0 = 4 * (tid >> 4);
            const float4 f = *(const float4*)&xbt[(size_t)(k0 + k) * C_ + c0];
            Bs[(c0 + 0) * LDM + k] = (__bf16)f.x;
            Bs[(c0 + 1) * LDM + k] = (__bf16)f.y;
            Bs[(c0 + 2) * LDM + k] = (__bf16)f.z;
            Bs[(c0 + 3) * LDM + k] = (__bf16)f.w;
        }
        __syncthreads();
        #pragma unroll
        for (int ks = 0; ks < 2; ++ks) {
            bf16x8 a0 = *(const bf16x8*)&As[(w * 32 +  0 + lr) * LDM + ks * 32 + lk * 8];
            bf16x8 a1 = *(const bf16x8*)&As[(w * 32 + 16 + lr) * LDM + ks * 32 + lk * 8];
            #pragma unroll
            for (int nj = 0; nj < 4; ++nj) {
                bf16x8 b = *(const bf16x8*)&Bs[(nj * 16 + lr) * LDM + ks * 32 + lk * 8];
                acc[0][nj] = __builtin_amdgcn_mfma_f32_16x16x32_bf16(a0, b, acc[0][nj], 0, 0, 0);
                acc[1][nj] = __builtin_amdgcn_mfma_f32_16x16x32_bf16(a1, b, acc[1][nj], 0, 0, 0);
            }
        }
    }
    __syncthreads();

    #pragma unroll
    for (int j = 0; j < 8; ++j) {
        const int r = rg + 16 * j;
        const float4 f = *(const float4*)&xbt[(size_t)(m0 + r) * C_ + 4 * c4];
        bf16x4 h = { (__bf16)(c1 * f.x), (__bf16)(c1 * f.y), (__bf16)(c1 * f.z), (__bf16)(c1 * f.w) };
        *(bf16x4*)&E[r * LDE + 64 + 4 * c4] = h;
    }
    #pragma unroll
    for (int mi = 0; mi < 2; ++mi)
        #pragma unroll
        for (int nj = 0; nj < 4; ++nj)
            #pragma unroll
            for (int q = 0; q < 4; ++q) {
                const int row = w * 32 + mi * 16 + lk * 4 + q;
                const int col = nj * 16 + lr;
                E[row * LDE + col] = (__bf16)(c2 * acc[mi][nj][q]);
            }
    __syncthreads();

    f32x4 oacc[2][4] = {};
    #pragma unroll
    for (int ks = 0; ks < 4; ++ks) {
        bf16x8 a0 = *(const bf16x8*)&E[(w * 32 +  0 + lr) * LDE + ks * 32 + lk * 8];
        bf16x8 a1 = *(const bf16x8*)&E[(w * 32 + 16 + lr) * LDE + ks * 32 + lk * 8];
        #pragma unroll
        for (int nj = 0; nj < 4; ++nj) {
            bf16x8 bw = *(const bf16x8*)&Wt[(nj * 16 + lr) * LDE + ks * 32 + lk * 8];
            oacc[0][nj] = __builtin_amdgcn_mfma_f32_16x16x32_bf16(a0, bw, oacc[0][nj], 0, 0, 0);
            oacc[1][nj] = __builtin_amdgcn_mfma_f32_16x16x32_bf16(a1, bw, oacc[1][nj], 0, 0, 0);
        }
    }
    float* obt = out + (size_t)bt * N_ * C_;
    #pragma unroll
    for (int nj = 0; nj < 4; ++nj) {
        const float bv = bias[nj * 16 + lr];
        #pragma unroll
        for (int mi = 0; mi < 2; ++mi)
            #pragma unroll
            for (int q = 0; q < 4; ++q) {
                const int row = w * 32 + mi * 16 + lk * 4 + q;
                obt[(size_t)(m0 + row) * C_ + nj * 16 + lr] = oacc[mi][nj][q] + bv;
            }
    }
}

extern "C" void kernel_launch(void* const* d_in, const int* in_sizes, int n_in,
                              void* d_out, int out_size, void* d_ws, size_t ws_size,
                              hipStream_t stream) {
    const float* x       = (const float*)d_in[0];
    const float* adj     = (const float*)d_in[1];
    const float* st_emb  = (const float*)d_in[2];
    const float* weights = (const float*)d_in[3];
    const float* bias    = (const float*)d_in[4];
    const float* W1      = (const float*)d_in[5];
    const float* b1      = (const float*)d_in[6];
    const float* W2      = (const float*)d_in[7];
    const float* b2      = (const float*)d_in[8];
    float* out = (float*)d_out;
    char* ws = (char*)d_ws;
    float* cbuf = (float*)(ws + WS_CBUF);

    if (ws_size >= WS_MID) {
        __bf16* WtB  = (__bf16*)(ws + WS_WTB);
        __bf16* adjb = (__bf16*)(ws + WS_ADJB);
        __bf16* P1T  = (__bf16*)(ws + WS_P1T);
        __bf16* P0S  = (__bf16*)(ws + WS_P0S);   // only valid in full tier
        lamw_kernel<<<1, 512, 0, stream>>>(st_emb, W1, b1, W2, b2, weights, cbuf, WtB);
        if (ws_size >= WS_FULL) {
            pcvt_kernel<true><<<3584, 256, 0, stream>>>(x, adj, WtB, cbuf, bias, adjb, P1T, P0S, out);
            dgcn_main8<true><<<768, 256, 0, stream>>>(adjb, P1T, P0S, cbuf, out);
        } else {
            pcvt_kernel<false><<<3584, 256, 0, stream>>>(x, adj, WtB, cbuf, bias, adjb, P1T, P0S, out);
            dgcn_main8<false><<<768, 256, 0, stream>>>(adjb, P1T, P0S, cbuf, out);
        }
    } else {
        lam_kernel<<<1, 384, 0, stream>>>(st_emb, W1, b1, W2, b2, cbuf);
        dgcn_fb<<<dim3(N_ / BM, B_ * T_), 256, 0, stream>>>(x, adj, weights, bias, cbuf, out);
    }
}

// Round 11
// 96.599 us; speedup vs baseline: 1.0950x; 1.0950x over previous
//
#include <hip/hip_runtime.h>
#include <hip/hip_bf16.h>

#define B_ 8
#define T_ 12
#define N_ 2048
#define C_ 64
#define BM 128
#define BK 64

typedef __attribute__((ext_vector_type(4))) float f32x4;
typedef __attribute__((ext_vector_type(4))) __bf16 bf16x4;
typedef __attribute__((ext_vector_type(8))) __bf16 bf16x8;

#define GAS __attribute__((address_space(1)))
#define LAS __attribute__((address_space(3)))

static __device__ __forceinline__ void gld_lds16(const void* g, void* l) {
    __builtin_amdgcn_global_load_lds((const GAS void*)g, (LAS void*)l, 16, 0, 0);
}

// ws layout (bytes)
#define WS_CBUF 0
#define WS_WTB  1024                                   // 16 KB
#define WS_ADJB 32768                                  // 8 MB (row-major bf16 adj)
#define WS_P1T  (32768 + 8388608)                      // 24 MB
#define WS_MID  ((size_t)WS_P1T + 25165824)            // 33,587,200 (proven available)

// ---------------- lambda MLP (fallback path) ----------------
__global__ void lam_kernel(const float* __restrict__ st, const float* __restrict__ W1,
                           const float* __restrict__ b1, const float* __restrict__ W2,
                           const float* __restrict__ b2, float* __restrict__ cbuf) {
    const int t = threadIdx.x >> 5;
    const int h = threadIdx.x & 31;
    if (t >= T_) return;
    float acc = b1[h];
    #pragma unroll 8
    for (int e = 0; e < 64; ++e) acc += st[t * 64 + e] * W1[e * 32 + h];
    float hv = fmaxf(acc, 0.f) * W2[h];
    #pragma unroll
    for (int off = 16; off; off >>= 1) hv += __shfl_down(hv, off, 32);
    if (h == 0) {
        float lam = 1.f + fmaxf(hv + b2[0], 0.f);
        cbuf[t]      = 2.f - 2.f / lam;
        cbuf[T_ + t] = 2.f / lam;
    }
}

// ---------------- lambda MLP + Wcat->bf16 + adj fp32->bf16 ----------------
// block 0: lambda + WtB ; blocks 1..1024: adj convert (512 thr x 8 elems)
__global__ void lamw_adj_kernel(const float* __restrict__ st, const float* __restrict__ W1,
                                const float* __restrict__ b1, const float* __restrict__ W2,
                                const float* __restrict__ b2, const float* __restrict__ weights,
                                const float* __restrict__ adj, float* __restrict__ cbuf,
                                __bf16* __restrict__ WtB, __bf16* __restrict__ adjb) {
    const int bid = blockIdx.x;
    const int tid = threadIdx.x;
    if (bid > 0) {
        const size_t i = ((size_t)(bid - 1) * 512 + tid) * 8;
        const float4 f0 = *(const float4*)&adj[i];
        const float4 f1 = *(const float4*)&adj[i + 4];
        bf16x8 h = { (__bf16)f0.x, (__bf16)f0.y, (__bf16)f0.z, (__bf16)f0.w,
                     (__bf16)f1.x, (__bf16)f1.y, (__bf16)f1.z, (__bf16)f1.w };
        *(bf16x8*)&adjb[i] = h;
        return;
    }
    const int t = tid >> 5;
    const int h = tid & 31;
    if (t < T_) {
        float acc = b1[h];
        #pragma unroll 8
        for (int e = 0; e < 64; ++e) acc += st[t * 64 + e] * W1[e * 32 + h];
        float hv = fmaxf(acc, 0.f) * W2[h];
        #pragma unroll
        for (int off = 16; off; off >>= 1) hv += __shfl_down(hv, off, 32);
        if (h == 0) {
            float lam = 1.f + fmaxf(hv + b2[0], 0.f);
            cbuf[t]      = 2.f - 2.f / lam;
            cbuf[T_ + t] = 2.f / lam;
        }
    }
    // WtB[o][k]: k<64 -> weights[1][k][o] (adj support), k>=64 -> weights[0][k-64][o] (identity)
    for (int e = tid; e < 64 * 128; e += 512) {
        int o = e >> 7, k = e & 127;
        float v = (k < 64) ? weights[4096 + k * 64 + o] : weights[(k - 64) * 64 + o];
        WtB[o * 128 + k] = (__bf16)v;
    }
}

// ---------------- P kernel: P1T = (x@W1)^T bf16 only ----------------
// 1536 blocks: one per (bt, 128-row tile)
__global__ __launch_bounds__(256, 4) void pcvt_kernel(
    const float* __restrict__ x, const __bf16* __restrict__ WtB,
    __bf16* __restrict__ P1T)
{
    __shared__ __align__(16) __bf16 T[64 * 128];   // transpose tile, o-rows of 256 B
    char* TB = (char*)T;
    const int bid = blockIdx.x;
    const int tid = threadIdx.x;
    const int bt = bid >> 4, n0 = (bid & 15) * 128;
    const int l = tid & 63, w = tid >> 6;
    const int lr = l & 15, lk = l >> 4;

    f32x4 p1[2][4] = {};
    #pragma unroll
    for (int ks = 0; ks < 2; ++ks) {
        bf16x8 a[2];
        #pragma unroll
        for (int mi = 0; mi < 2; ++mi) {
            const float* xs = x + ((size_t)bt * N_ + n0 + w * 32 + mi * 16 + lr) * C_ + ks * 32 + lk * 8;
            float4 f0 = *(const float4*)xs;
            float4 f1 = *(const float4*)(xs + 4);
            a[mi] = { (__bf16)f0.x, (__bf16)f0.y, (__bf16)f0.z, (__bf16)f0.w,
                      (__bf16)f1.x, (__bf16)f1.y, (__bf16)f1.z, (__bf16)f1.w };
        }
        #pragma unroll
        for (int nj = 0; nj < 4; ++nj) {
            bf16x8 b1v = *(const bf16x8*)(WtB + (nj * 16 + lr) * 128 + ks * 32 + lk * 8);
            #pragma unroll
            for (int mi = 0; mi < 2; ++mi)
                p1[mi][nj] = __builtin_amdgcn_mfma_f32_16x16x32_bf16(a[mi], b1v, p1[mi][nj], 0, 0, 0);
        }
    }
    // P1 -> LDS (swizzled) -> coalesced transposed write-out
    #pragma unroll
    for (int nj = 0; nj < 4; ++nj) {
        const int o = nj * 16 + lr;
        #pragma unroll
        for (int mi = 0; mi < 2; ++mi)
            #pragma unroll
            for (int q = 0; q < 4; ++q) {
                const int row = w * 32 + mi * 16 + lk * 4 + q;
                *(__bf16*)(TB + o * 256 + ((row * 2) ^ ((o & 7) << 4))) = (__bf16)p1[mi][nj][q];
            }
    }
    __syncthreads();
    {
        const int o = tid >> 2, seg = tid & 3;
        __bf16* dst = P1T + ((size_t)bt * 64 + o) * N_ + n0 + seg * 32;
        #pragma unroll
        for (int i = 0; i < 4; ++i) {
            const int chunk = seg * 64 + i * 16;
            *(bf16x8*)(dst + i * 8) = *(const bf16x8*)(TB + o * 256 + (chunk ^ ((o & 7) << 4)));
        }
    }
}

// ---------------- main kernel: out = c2*(adj @ P1) + c1*(x @ W0) + bias ----------------
// Round-9 proven K-loop: 128x128 tile (2 bt), single 32KB buffer, two syncthreads/kt,
// gld_lds A+B, 3 blocks/CU. Grid 768 1D with XCD swizzle (R10-verified mapping).
// Fused P0 epilogue: acc *= c2, then MFMA (c1*x)@W0 into same acc, +bias, single store.
__global__ __launch_bounds__(256, 3) void dgcn_main9(
    const __bf16* __restrict__ adjb, const __bf16* __restrict__ P1T,
    const float* __restrict__ x, const __bf16* __restrict__ WtB,
    const float* __restrict__ bias, const float* __restrict__ cbuf,
    float* __restrict__ out)
{
    __shared__ __align__(16) __bf16 smem[16384];   // 32768 B: A [0,16K), B [16K,32K)
    char* sb = (char*)smem;

    // XCD swizzle: id%8 = XCD; each XCD owns 6 contiguous btg x 16 m-tiles (R10-verified)
    const int id  = blockIdx.x;                    // 0..767
    const int xcd = id & 7;
    const int wi  = id >> 3;                       // 0..95
    const int btg = xcd * 6 + (wi >> 4);           // 0..47
    const int m0  = (wi & 15) * BM;

    const int tid = threadIdx.x;
    const int l   = tid & 63, w = tid >> 6;
    const int wr  = w >> 1, wc = w & 1;
    const int lr  = l & 15, lk = l >> 4;

    // per-lane inverse-swizzled global sources for global_load_lds (round-3/9 verified)
    const __bf16* srcA[4];
    const __bf16* srcB[4];
    #pragma unroll
    for (int i = 0; i < 4; ++i) {
        int s = (w * 4 + i) * 64 + l;              // 0..1023
        int r = s >> 3, j = s & 7;                 // A: 128 rows x 128 B
        srcA[i] = adjb + (size_t)(m0 + r) * N_ + 8 * (j ^ (r & 7));
        int bb = s >> 9, o = (s >> 3) & 63;        // B: 2 bt x 64 o-rows x 128 B
        srcB[i] = P1T + ((size_t)(btg * 2 + bb) * 64 + o) * N_ + 8 * (j ^ (o & 7));
    }

    f32x4 acc[4][4] = {};

    for (int kt = 0; kt < N_ / BK; ++kt) {
        __syncthreads();                           // prev frags consumed
        #pragma unroll
        for (int i = 0; i < 4; ++i) {
            gld_lds16(srcA[i], sb + (w * 4 + i) * 1024);
            gld_lds16(srcB[i], sb + 16384 + (w * 4 + i) * 1024);
            srcA[i] += BK;
            srcB[i] += BK;
        }
        __syncthreads();                           // compiler drains vmcnt(0) before barrier
        #pragma unroll
        for (int ks = 0; ks < 2; ++ks) {
            const int kb = ks * 64 + lk * 16;
            bf16x8 a[4];
            #pragma unroll
            for (int mi = 0; mi < 4; ++mi) {
                int rr = wr * 64 + mi * 16 + lr;
                a[mi] = *(const bf16x8*)(sb + rr * 128 + (kb ^ ((rr & 7) << 4)));
            }
            #pragma unroll
            for (int nj = 0; nj < 4; ++nj) {
                int cc = nj * 16 + lr;
                bf16x8 b = *(const bf16x8*)(sb + 16384 + wc * 8192 + cc * 128 + (kb ^ ((cc & 7) << 4)));
                #pragma unroll
                for (int mi = 0; mi < 4; ++mi)
                    acc[mi][nj] = __builtin_amdgcn_mfma_f32_16x16x32_bf16(a[mi], b, acc[mi][nj], 0, 0, 0);
            }
        }
    }

    // ---- fused P0 epilogue ----
    const int btA = btg * 2 + wc;                  // wave wc owns this bt (B-panel split)
    const float c1 = cbuf[btA % T_];
    const float c2 = cbuf[T_ + (btA % T_)];

    // A-frags of c1*x[btA] (rows m0+wr*64+mi*16+lr, cols ks*32+lk*8), fp32->bf16 with c1 folded
    bf16x8 xa[4][2];
    #pragma unroll
    for (int mi = 0; mi < 4; ++mi)
        #pragma unroll
        for (int ks = 0; ks < 2; ++ks) {
            const float* xs = x + ((size_t)btA * N_ + m0 + wr * 64 + mi * 16 + lr) * C_ + ks * 32 + lk * 8;
            float4 f0 = *(const float4*)xs;
            float4 f1 = *(const float4*)(xs + 4);
            xa[mi][ks] = { (__bf16)(c1 * f0.x), (__bf16)(c1 * f0.y),
                           (__bf16)(c1 * f0.z), (__bf16)(c1 * f0.w),
                           (__bf16)(c1 * f1.x), (__bf16)(c1 * f1.y),
                           (__bf16)(c1 * f1.z), (__bf16)(c1 * f1.w) };
        }
    // acc = c2*acc, then acc += (c1*x) @ W0   (W0 frags contiguous at WtB[o][64+..])
    #pragma unroll
    for (int mi = 0; mi < 4; ++mi)
        #pragma unroll
        for (int nj = 0; nj < 4; ++nj)
            acc[mi][nj] *= c2;
    #pragma unroll
    for (int ks = 0; ks < 2; ++ks)
        #pragma unroll
        for (int nj = 0; nj < 4; ++nj) {
            bf16x8 bw = *(const bf16x8*)(WtB + (nj * 16 + lr) * 128 + 64 + ks * 32 + lk * 8);
            #pragma unroll
            for (int mi = 0; mi < 4; ++mi)
                acc[mi][nj] = __builtin_amdgcn_mfma_f32_16x16x32_bf16(xa[mi][ks], bw, acc[mi][nj], 0, 0, 0);
        }
    // store once: out = acc + bias
    #pragma unroll
    for (int nj = 0; nj < 4; ++nj) {
        const int o = nj * 16 + lr;
        const float bv = bias[o];
        #pragma unroll
        for (int mi = 0; mi < 4; ++mi)
            #pragma unroll
            for (int q = 0; q < 4; ++q) {
                const int row = wr * 64 + mi * 16 + lk * 4 + q;
                out[((size_t)btA * N_ + m0 + row) * C_ + o] = acc[mi][nj][q] + bv;
            }
    }
}

// ---------------- fallback (round-1 verified) ----------------
#define LDM 72
#define LDE 136
__global__ __launch_bounds__(256, 3) void dgcn_fb(
    const float* __restrict__ x, const float* __restrict__ adj,
    const float* __restrict__ weights, const float* __restrict__ bias,
    const float* __restrict__ cbuf, float* __restrict__ out)
{
    __shared__ __align__(16) __bf16 smem[BM * LDE];
    __shared__ __align__(16) __bf16 Wt[64 * LDE];
    __bf16* As = smem;
    __bf16* Bs = smem + BM * LDM;
    __bf16* E  = smem;

    const int mtile = blockIdx.x;
    const int bt    = blockIdx.y;
    const int tloc  = bt % T_;
    const int m0    = mtile * BM;
    const int tid   = threadIdx.x;
    const int lane  = tid & 63;
    const int w     = tid >> 6;

    const float c1 = cbuf[tloc];
    const float c2 = cbuf[T_ + tloc];
    const float* xbt = x + (size_t)bt * N_ * C_;

    for (int e = tid; e < 2 * 64 * 64; e += 256) {
        int kk = e >> 6, o = e & 63;
        float v = (kk < 64) ? weights[4096 + kk * 64 + o] : weights[(kk - 64) * 64 + o];
        Wt[o * LDE + kk] = (__bf16)v;
    }

    f32x4 acc[2][4] = {};
    const int c4 = tid & 15;
    const int rg = tid >> 4;
    const int lr = lane & 15;
    const int lk = lane >> 4;

    for (int kt = 0; kt < N_ / 64; ++kt) {
        const int k0 = kt * 64;
        __syncthreads();
        #pragma unroll
        for (int j = 0; j < 8; ++j) {
            const int r = rg + 16 * j;
            const float4 f = *(const float4*)&adj[(size_t)(m0 + r) * N_ + k0 + 4 * c4];
            bf16x4 h = { (__bf16)f.x, (__bf16)f.y, (__bf16)f.z, (__bf16)f.w };
            *(bf16x4*)&As[r * LDM + 4 * c4] = h;
        }
        #pragma unroll
        for (int j = 0; j < 4; ++j) {
            const int k  = (tid & 15) + 16 * j;
            const int c0 = 4 * (tid >> 4);
            const float4 f = *(const float4*)&xbt[(size_t)(k0 + k) * C_ + c0];
            Bs[(c0 + 0) * LDM + k] = (__bf16)f.x;
            Bs[(c0 + 1) * LDM + k] = (__bf16)f.y;
            Bs[(c0 + 2) * LDM + k] = (__bf16)f.z;
            Bs[(c0 + 3) * LDM + k] = (__bf16)f.w;
        }
        __syncthreads();
        #pragma unroll
        for (int ks = 0; ks < 2; ++ks) {
            bf16x8 a0 = *(const bf16x8*)&As[(w * 32 +  0 + lr) * LDM + ks * 32 + lk * 8];
            bf16x8 a1 = *(const bf16x8*)&As[(w * 32 + 16 + lr) * LDM + ks * 32 + lk * 8];
            #pragma unroll
            for (int nj = 0; nj < 4; ++nj) {
                bf16x8 b = *(const bf16x8*)&Bs[(nj * 16 + lr) * LDM + ks * 32 + lk * 8];
                acc[0][nj] = __builtin_amdgcn_mfma_f32_16x16x32_bf16(a0, b, acc[0][nj], 0, 0, 0);
                acc[1][nj] = __builtin_amdgcn_mfma_f32_16x16x32_bf16(a1, b, acc[1][nj], 0, 0, 0);
            }
        }
    }
    __syncthreads();

    #pragma unroll
    for (int j = 0; j < 8; ++j) {
        const int r = rg + 16 * j;
        const float4 f = *(const float4*)&xbt[(size_t)(m0 + r) * C_ + 4 * c4];
        bf16x4 h = { (__bf16)(c1 * f.x), (__bf16)(c1 * f.y), (__bf16)(c1 * f.z), (__bf16)(c1 * f.w) };
        *(bf16x4*)&E[r * LDE + 64 + 4 * c4] = h;
    }
    #pragma unroll
    for (int mi = 0; mi < 2; ++mi)
        #pragma unroll
        for (int nj = 0; nj < 4; ++nj)
            #pragma unroll
            for (int q = 0; q < 4; ++q) {
                const int row = w * 32 + mi * 16 + lk * 4 + q;
                const int col = nj * 16 + lr;
                E[row * LDE + col] = (__bf16)(c2 * acc[mi][nj][q]);
            }
    __syncthreads();

    f32x4 oacc[2][4] = {};
    #pragma unroll
    for (int ks = 0; ks < 4; ++ks) {
        bf16x8 a0 = *(const bf16x8*)&E[(w * 32 +  0 + lr) * LDE + ks * 32 + lk * 8];
        bf16x8 a1 = *(const bf16x8*)&E[(w * 32 + 16 + lr) * LDE + ks * 32 + lk * 8];
        #pragma unroll
        for (int nj = 0; nj < 4; ++nj) {
            bf16x8 bw = *(const bf16x8*)&Wt[(nj * 16 + lr) * LDE + ks * 32 + lk * 8];
            oacc[0][nj] = __builtin_amdgcn_mfma_f32_16x16x32_bf16(a0, bw, oacc[0][nj], 0, 0, 0);
            oacc[1][nj] = __builtin_amdgcn_mfma_f32_16x16x32_bf16(a1, bw, oacc[1][nj], 0, 0, 0);
        }
    }
    float* obt = out + (size_t)bt * N_ * C_;
    #pragma unroll
    for (int nj = 0; nj < 4; ++nj) {
        const float bv = bias[nj * 16 + lr];
        #pragma unroll
        for (int mi = 0; mi < 2; ++mi)
            #pragma unroll
            for (int q = 0; q < 4; ++q) {
                const int row = w * 32 + mi * 16 + lk * 4 + q;
                obt[(size_t)(m0 + row) * C_ + nj * 16 + lr] = oacc[mi][nj][q] + bv;
            }
    }
}

extern "C" void kernel_launch(void* const* d_in, const int* in_sizes, int n_in,
                              void* d_out, int out_size, void* d_ws, size_t ws_size,
                              hipStream_t stream) {
    const float* x       = (const float*)d_in[0];
    const float* adj     = (const float*)d_in[1];
    const float* st_emb  = (const float*)d_in[2];
    const float* weights = (const float*)d_in[3];
    const float* bias    = (const float*)d_in[4];
    const float* W1      = (const float*)d_in[5];
    const float* b1      = (const float*)d_in[6];
    const float* W2      = (const float*)d_in[7];
    const float* b2      = (const float*)d_in[8];
    float* out = (float*)d_out;
    char* ws = (char*)d_ws;
    float* cbuf = (float*)(ws + WS_CBUF);

    if (ws_size >= WS_MID) {
        __bf16* WtB  = (__bf16*)(ws + WS_WTB);
        __bf16* adjb = (__bf16*)(ws + WS_ADJB);
        __bf16* P1T  = (__bf16*)(ws + WS_P1T);
        lamw_adj_kernel<<<1025, 512, 0, stream>>>(st_emb, W1, b1, W2, b2, weights, adj, cbuf, WtB, adjb);
        pcvt_kernel<<<1536, 256, 0, stream>>>(x, WtB, P1T);
        dgcn_main9<<<768, 256, 0, stream>>>(adjb, P1T, x, WtB, bias, cbuf, out);
    } else {
        lam_kernel<<<1, 384, 0, stream>>>(st_emb, W1, b1, W2, b2, cbuf);
        dgcn_fb<<<dim3(N_ / BM, B_ * T_), 256, 0, stream>>>(x, adj, weights, bias, cbuf, out);
    }
}